// Round 13
// baseline (117.604 us; speedup 1.0000x reference)
//
#include <hip/hip_runtime.h>
#include <hip/hip_bf16.h>
#include <math.h>

#define FRAME_LEN 882
#define FRAME_HOP 441
#define NFFT 2048
#define NFRAMES 999
#define NBATCH 16
#define NMEL 60
#define WAVE_LEN 441000
#define PRE_EMPH 0.97f
#define EPS 1e-10f
#define NROWS (NBATCH * NFRAMES)     // 15984 = 999 panels x 16 rows
#define NPANEL 999
#define KPAD 1056                    // 33*32
#define NKC 33
#define PANEL_ELEMS (NKC * 512)      // 16896 bf16 per panel (frag-linear)
#define PI_F 3.14159265358979323846f

// LDS index padding: +1 per 16
#define PADI(i) ((i) + ((i) >> 4))

// Frag-linear offset of (row m in panel, bin k)
__device__ __forceinline__ int frag_off(int m, int k) {
  return ((k >> 5) * 512) | (((k >> 3) & 3) * 128) | (m * 8) | (k & 7);
}

// Packed complex types
typedef float vf2 __attribute__((ext_vector_type(2)));
typedef __fp16 hf2 __attribute__((ext_vector_type(2)));   // matches cvt_pkrtz return type
__device__ __forceinline__ vf2 mkv(float x, float y){ vf2 r; r.x = x; r.y = y; return r; }
__device__ __forceinline__ vf2 cmul(vf2 a, vf2 b){ return a.xx * b + mkv(-a.y, a.y) * b.yx; }
__device__ __forceinline__ vf2 rotni(vf2 z){ return mkv(z.y, -z.x); }  // z * (-i)

// fp16 pack/unpack for LDS exchange (v_cvt_pkrtz_f16_f32 : 1 instr)
__device__ __forceinline__ hf2 packc(vf2 v) { return __builtin_amdgcn_cvt_pkrtz(v.x, v.y); }
__device__ __forceinline__ vf2 unpackc(hf2 h) { return mkv((float)h.x, (float)h.y); }

// Four consecutive DIF radix-2 stages (halves 8S,4S,2S,S), 16 elems/thread.
// Thread owns e_k = Q*16S + k*S + r. All twiddles from t1 = e^{-i*pi*r/(8S)}.
// (R4/R11-verified.)
__device__ __forceinline__ void dif_group16(vf2* x, vf2 t1, bool zerohi) {
  const vf2 C81 = mkv(0.9238795325f, -0.3826834324f);
  const vf2 C82 = mkv(0.7071067812f, -0.7071067812f);
  const vf2 C83 = mkv(0.3826834324f, -0.9238795325f);
  vf2 w0 = t1, w1 = cmul(t1, C81), w2 = cmul(t1, C82), w3 = cmul(t1, C83);
  vf2 ws1[8] = {w0, w1, w2, w3, rotni(w0), rotni(w1), rotni(w2), rotni(w3)};
  if (zerohi) {
#pragma unroll
    for (int k = 0; k < 8; ++k) x[k + 8] = cmul(x[k], ws1[k]);
  } else {
#pragma unroll
    for (int k = 0; k < 8; ++k) {
      vf2 u = x[k], v = x[k + 8];
      x[k] = u + v;
      x[k + 8] = cmul(u - v, ws1[k]);
    }
  }
  vf2 t2 = cmul(t1, t1);
  vf2 v1 = cmul(t2, C82);
  vf2 ws2[4] = {t2, v1, rotni(t2), rotni(v1)};
#pragma unroll
  for (int h = 0; h < 2; ++h) {
#pragma unroll
    for (int k = 0; k < 4; ++k) {
      vf2 u = x[h*8 + k], v = x[h*8 + k + 4];
      x[h*8 + k] = u + v;
      x[h*8 + k + 4] = cmul(u - v, ws2[k]);
    }
  }
  vf2 t4 = cmul(t2, t2);
  vf2 t4r = rotni(t4);
#pragma unroll
  for (int h = 0; h < 4; ++h) {
    vf2 a = x[h*4 + 0], b = x[h*4 + 2];
    x[h*4 + 0] = a + b; x[h*4 + 2] = cmul(a - b, t4);
    a = x[h*4 + 1]; b = x[h*4 + 3];
    x[h*4 + 1] = a + b; x[h*4 + 3] = cmul(a - b, t4r);
  }
  vf2 t8 = cmul(t4, t4);
#pragma unroll
  for (int j = 0; j < 8; ++j) {
    vf2 a = x[2*j], b = x[2*j + 1];
    x[2*j] = a + b; x[2*j + 1] = cmul(a - b, t8);
  }
}

// Final 3 DIF stages (halves 4,2,1) on 8 consecutive elements (verified).
__device__ __forceinline__ void dif8(vf2* y) {
  const vf2 c1 = mkv(0.7071067812f, -0.7071067812f);
  const vf2 c3 = mkv(-0.7071067812f, -0.7071067812f);
  vf2 u, v;
  u=y[0]; v=y[4]; y[0]=u+v; y[4]=u-v;
  u=y[1]; v=y[5]; y[1]=u+v; y[5]=cmul(u-v, c1);
  u=y[2]; v=y[6]; y[2]=u+v; y[6]=rotni(u-v);
  u=y[3]; v=y[7]; y[3]=u+v; y[7]=cmul(u-v, c3);
  u=y[0]; v=y[2]; y[0]=u+v; y[2]=u-v;
  u=y[1]; v=y[3]; y[1]=u+v; y[3]=rotni(u-v);
  u=y[4]; v=y[6]; y[4]=u+v; y[6]=u-v;
  u=y[5]; v=y[7]; y[5]=u+v; y[7]=rotni(u-v);
  u=y[0]; v=y[1]; y[0]=u+v; y[1]=u-v;
  u=y[2]; v=y[3]; y[2]=u+v; y[3]=u-v;
  u=y[4]; v=y[5]; y[4]=u+v; y[5]=u-v;
  u=y[6]; v=y[7]; y[6]=u+v; y[7]=u-v;
}

// Kernel 1 (merged): blocks [0,4000) each run TWO 2048-pt frame-pair FFTs
// side-by-side; LDS exchanges are PACKED FP16 (half2 per complex): LDS block
// 17.4 KB total -> 8 blocks/CU (32 waves), LDS traffic 3x below the radix-8
// f32 version. Blocks [4000,4064) do the filter->bf16 fragment conversion.
__global__ __launch_bounds__(256) void fft_pow_kernel(
    const float* __restrict__ wav, const float* __restrict__ filt,
    __hip_bfloat16* __restrict__ powrF, __hip_bfloat16* __restrict__ filtbF)
{
  __shared__ hf2 lds2[2][NFFT + (NFFT >> 4)];   // 2 x 2176 x 4 B = 17408 B
  const int id = blockIdx.x;

  if (id >= 4000) {
    const int mm = id - 4000;  // 0..63
    __hip_bfloat16* qp = filtbF + (size_t)(mm >> 4) * PANEL_ELEMS;
    const int m = mm & 15;
    for (int k = threadIdx.x; k < KPAD; k += 256) {
      float v = (mm < NMEL && k < 1025) ? filt[mm * 1025 + k] : 0.f;
      qp[frag_off(m, k)] = __float2bfloat16(v);
    }
    return;
  }

  const int t   = threadIdx.x;
  const int fid = t >> 7;            // which of the 2 FFTs in this block
  const int tt  = t & 127;           // thread id within the FFT (0..127)
  hf2* lds = lds2[fid];

  const int P  = id * 2 + fid;       // frame-pair index 0..7999
  const int b  = P & 15;
  const int t0 = 2 * (P >> 4), t1f = t0 + 1;
  const bool has1 = (t1f < NFRAMES);
  const float* w = wav + (size_t)b * WAVE_LEN;
  const int s0 = t0 * FRAME_HOP;
  int s1 = t1f * FRAME_HOP;
  if (s1 > WAVE_LEN - FRAME_LEN) s1 = WAVE_LEN - FRAME_LEN;

  vf2 x[16];
  // ---- load + pre-emphasis + Hamming: element i = k*128 + tt ----
  {
    float sB, cB, sD, cD;
    __sincosf(6.283185307179586f * (float)tt / 881.0f, &sB, &cB);
    __sincosf(6.283185307179586f * 128.0f / 881.0f, &sD, &cD);
    vf2 cur  = mkv(cB, sB);
    vf2 step = mkv(cD, sD);
#pragma unroll
    for (int k = 0; k < 7; ++k) {    // k>=7 -> i>=896 > 881 -> zero
      int i = k * 128 + tt;
      float v1 = 0.f, v2 = 0.f;
      if (i < FRAME_LEN) {
        float win = 0.54f - 0.46f * cur.x;
        int s = s0 + i;
        float e1 = (s > 0) ? (w[s] - PRE_EMPH * w[s - 1]) : w[s];
        v1 = e1 * win;
        int ss = s1 + i;             // ss >= 441 > 0 always
        v2 = (w[ss] - PRE_EMPH * w[ss - 1]) * win;
      }
      x[k] = mkv(v1, v2);
      cur = cmul(cur, step);
    }
#pragma unroll
    for (int k = 7; k < 16; ++k) x[k] = mkv(0.f, 0.f);
  }

  // ---- G0: halves 1024,512,256,128 (S=128, r=tt): t1 = e^{-i*pi*tt/1024}
  {
    float sA, cA;
    __sincosf(-PI_F * (float)tt / 1024.0f, &sA, &cA);
    dif_group16(x, mkv(cA, sA), true);   // x[8..15] zero on entry
  }
#pragma unroll
  for (int k = 0; k < 16; ++k) lds[PADI(k * 128 + tt)] = packc(x[k]);
  __syncthreads();

  // ---- G1: halves 64,32,16,8 (S=8): Q = tt>>3, r = tt&7; t1 = e^{-i*pi*r/64}
  {
    const int Q = tt >> 3, r = tt & 7;
    const int base = Q * 128 + r;
#pragma unroll
    for (int k = 0; k < 16; ++k) x[k] = unpackc(lds[PADI(base + k * 8)]);
    float sA, cA;
    __sincosf(-PI_F * (float)r / 64.0f, &sA, &cA);
    dif_group16(x, mkv(cA, sA), false);
    __syncthreads();
#pragma unroll
    for (int k = 0; k < 16; ++k) lds[PADI(base + k * 8)] = packc(x[k]);
  }
  __syncthreads();

  // ---- G2: halves 4,2,1 — two 8-point const-twiddle FFTs on consecutive runs
  {
    vf2 ya[8], yb[8];
#pragma unroll
    for (int j = 0; j < 8; ++j) {
      ya[j] = unpackc(lds[PADI(16 * tt + j)]);
      yb[j] = unpackc(lds[PADI(16 * tt + 8 + j)]);
    }
    dif8(ya);
    dif8(yb);
    __syncthreads();
#pragma unroll
    for (int j = 0; j < 8; ++j) {
      lds[PADI(16 * tt + j)] = packc(ya[j]);
      lds[PADI(16 * tt + 8 + j)] = packc(yb[j]);
    }
  }
  __syncthreads();

  // ---- power separation + bf16 store in FRAGMENT order ----
  const int r0g = b * NFRAMES + t0;
  const int r1g = r0g + 1;
  __hip_bfloat16* q0 = powrF + (size_t)(r0g >> 4) * PANEL_ELEMS;
  const int m0 = r0g & 15;
  __hip_bfloat16* q1 = powrF + (size_t)(r1g >> 4) * PANEL_ELEMS;
  const int m1 = r1g & 15;
#pragma unroll
  for (int c = 0; c < 8; ++c) {
    int f = c * 128 + tt;
    int j1 = (int)(__brev((unsigned)f) >> 21);
    int j2 = (int)(__brev((unsigned)((NFFT - f) & (NFFT - 1))) >> 21);
    vf2 z = unpackc(lds[PADI(j1)]);
    vf2 y = unpackc(lds[PADI(j2)]);
    float f1r = z.x + y.x, f1i = z.y - y.y;
    float f2r = z.y + y.y, f2i = y.x - z.x;
    float pw1 = 0.25f * (f1r * f1r + f1i * f1i);
    float pw2 = 0.25f * (f2r * f2r + f2i * f2i);
    q0[frag_off(m0, f)] = __float2bfloat16(pw1);
    if (has1) q1[frag_off(m1, f)] = __float2bfloat16(pw2);
  }
  if (tt == 0) {
    vf2 z = unpackc(lds[PADI(1)]);   // brev(1024) = 1; bin 1024 self-conjugate
    q0[frag_off(m0, 1024)] = __float2bfloat16(z.x * z.x);
    if (has1) q1[frag_off(m1, 1024)] = __float2bfloat16(z.y * z.y);
  }
  if (tt < KPAD - 1025) {
    int f = 1025 + tt;
    q0[frag_off(m0, f)] = __float2bfloat16(0.f);
    if (has1) q1[frag_off(m1, f)] = __float2bfloat16(0.f);
  }
}

// Kernel 2: mel GEMM, gather-free, 999 blocks, two K-chains (R8-verified).
typedef __attribute__((ext_vector_type(8))) short short8x;
typedef __attribute__((ext_vector_type(4))) float float4x;

__global__ __launch_bounds__(256) void melgemm_kernel(
    const __hip_bfloat16* __restrict__ powrF,
    const __hip_bfloat16* __restrict__ filtbF,
    float* __restrict__ logmelT)
{
  const int wave = threadIdx.x >> 6, lane = threadIdx.x & 63;
  const int p = blockIdx.x;                       // panel = rows [16p, 16p+16)
  const __hip_bfloat16* pA = powrF + (size_t)p * PANEL_ELEMS + lane * 8;
  const __hip_bfloat16* pB = filtbF + (size_t)wave * PANEL_ELEMS + lane * 8;

  float4x acc0 = {0.f, 0.f, 0.f, 0.f};
  float4x acc1 = {0.f, 0.f, 0.f, 0.f};
#pragma unroll 4
  for (int kc = 0; kc < 16; ++kc) {
    short8x a0 = *(const short8x*)(pA + kc * 512);
    short8x b0 = *(const short8x*)(pB + kc * 512);
    short8x a1 = *(const short8x*)(pA + (kc + 16) * 512);
    short8x b1 = *(const short8x*)(pB + (kc + 16) * 512);
    acc0 = __builtin_amdgcn_mfma_f32_16x16x32_bf16(a0, b0, acc0, 0, 0, 0);
    acc1 = __builtin_amdgcn_mfma_f32_16x16x32_bf16(a1, b1, acc1, 0, 0, 0);
  }
  {
    short8x a = *(const short8x*)(pA + 32 * 512);
    short8x bf = *(const short8x*)(pB + 32 * 512);
    acc0 = __builtin_amdgcn_mfma_f32_16x16x32_bf16(a, bf, acc0, 0, 0, 0);
  }

  const int mel = wave * 16 + (lane & 15);
  const int rsub = (lane >> 4) * 4;
  if (mel < NMEL) {
#pragma unroll
    for (int reg = 0; reg < 4; ++reg) {
      int row = p * 16 + rsub + reg;
      float vv = acc0[reg] + acc1[reg];
      logmelT[(size_t)mel * NROWS + row] = __logf(vv + EPS);
    }
  }
}

// Kernel 3: stats on transposed logmel (unchanged, verified).
__global__ __launch_bounds__(256) void stats_kernel(
    const float* __restrict__ lmT, float* __restrict__ out)
{
  __shared__ float red[4];
  const int j   = blockIdx.x;   // 0..89
  const int b   = blockIdx.y;   // 0..15
  const int tid = threadIdx.x;
  const int base = b * NFRAMES;
  const float inv_sq2 = 0.7071067811865475f;
  const bool v3 = (tid < NFRAMES - 768);

  float f0, f1, f2, f3;
  if (j < 30) {
    const float* e = lmT + (size_t)(2 * j) * NROWS + base;
    const float* o = lmT + (size_t)(2 * j + 1) * NROWS + base;
    f0 = (e[tid]       + o[tid])       * inv_sq2;
    f1 = (e[tid + 256] + o[tid + 256]) * inv_sq2;
    f2 = (e[tid + 512] + o[tid + 512]) * inv_sq2;
    f3 = v3 ? (e[tid + 768] + o[tid + 768]) * inv_sq2 : 0.f;
  } else if (j < 60) {
    const int m = j - 30;
    const float* e = lmT + (size_t)(2 * m) * NROWS + base;
    const float* o = lmT + (size_t)(2 * m + 1) * NROWS + base;
    auto dl = [&](int t) -> float {
      int tp = (t + 1 > NFRAMES - 1) ? (NFRAMES - 1) : (t + 1);
      int tm = (t - 1 < 0) ? 0 : (t - 1);
      return ((e[tp] + o[tp]) - (e[tm] + o[tm])) * inv_sq2;
    };
    f0 = dl(tid);
    f1 = dl(tid + 256);
    f2 = dl(tid + 512);
    f3 = v3 ? dl(tid + 768) : 0.f;
  } else {
    const int m = j - 60;
    const float* e = lmT + (size_t)(2 * m) * NROWS + base;
    const float* o = lmT + (size_t)(2 * m + 1) * NROWS + base;
    f0 = (e[tid]       - o[tid])       * inv_sq2;
    f1 = (e[tid + 256] - o[tid + 256]) * inv_sq2;
    f2 = (e[tid + 512] - o[tid + 512]) * inv_sq2;
    f3 = v3 ? (e[tid + 768] - o[tid + 768]) * inv_sq2 : 0.f;
  }

  float s = f0 + f1 + f2 + f3;
  for (int o2 = 32; o2 > 0; o2 >>= 1) s += __shfl_xor(s, o2, 64);
  if ((tid & 63) == 0) red[tid >> 6] = s;
  __syncthreads();
  float mean = (red[0] + red[1] + red[2] + red[3]) / (float)NFRAMES;
  __syncthreads();

  float d0 = f0 - mean, d1 = f1 - mean, d2 = f2 - mean;
  float d3 = v3 ? (f3 - mean) : 0.f;
  float s2 = d0 * d0 + d1 * d1 + d2 * d2 + d3 * d3;
  for (int o2 = 32; o2 > 0; o2 >>= 1) s2 += __shfl_xor(s2, o2, 64);
  if ((tid & 63) == 0) red[tid >> 6] = s2;
  __syncthreads();
  float var = (red[0] + red[1] + red[2] + red[3]) / (float)(NFRAMES - 1);

  if (tid == 0) {
    out[b * 180 + j]      = mean;
    out[b * 180 + 90 + j] = sqrtf(var);
  }
}

extern "C" void kernel_launch(void* const* d_in, const int* in_sizes, int n_in,
                              void* d_out, int out_size, void* d_ws, size_t ws_size,
                              hipStream_t stream) {
  const float* wav  = (const float*)d_in[0];   // (16, 441000) f32
  const float* filt = (const float*)d_in[1];   // (60, 1025) f32
  float* out = (float*)d_out;                  // (16, 180) f32

  // ws: powrF bf16 [999 panels][16896], filtbF bf16 [4][16896], logmelT f32 [60][NROWS]
  unsigned char* ws = (unsigned char*)d_ws;
  __hip_bfloat16* powrF  = (__hip_bfloat16*)(ws);
  size_t off = (size_t)NPANEL * PANEL_ELEMS * 2;              // 33,758,208
  __hip_bfloat16* filtbF = (__hip_bfloat16*)(ws + off);
  off += (size_t)4 * PANEL_ELEMS * 2;                         // +135,168
  float* logmelT = (float*)(ws + off);                        // +3,836,160 => ~37.7 MB

  fft_pow_kernel<<<4064, 256, 0, stream>>>(wav, filt, powrF, filtbF);
  melgemm_kernel<<<NPANEL, 256, 0, stream>>>(powrF, filtbF, logmelT);
  stats_kernel<<<dim3(90, NBATCH), 256, 0, stream>>>(logmelT, out);
}